// Round 13
// baseline (51.548 us; speedup 1.0000x reference)
//
#include <hip/hip_runtime.h>
#include <hip/hip_fp16.h>

#define H    256
#define W    256
#define WH   129            // W/2 + 1
#define VLEN 182            // max radial bin + 1
#define NIMG 64             // 32 pred + 32 target
#define TWO_PI 6.283185307179586f
#define ZSTR 516            // zbuf row stride in floats (516%32==4 -> lp rows on distinct banks)

// Integer-exact floor(sqrt) for s2 <= 32768: v_sqrt_f32 trunc is off by at
// most 1; two branchless fixups.
__device__ __forceinline__ int isqrt_fast(int s2) {
    int r = (int)__builtin_amdgcn_sqrtf((float)s2);
    r -= (r * r > s2);
    r += ((r + 1) * (r + 1) <= s2);
    return r;
}

__device__ __forceinline__ float2 cmul(float2 a, float2 b) {
    return make_float2(a.x * b.x - a.y * b.y, a.x * b.y + a.y * b.x);
}

// 256-point DIF FFT held by one 64-lane wave; thread t owns positions
// i = t + 64r (r=0..3). On exit, position i holds X[bitrev8(i)].
__device__ __forceinline__ void wfft256(float2 z[4], int t) {
    float s, c;
    // m=256: reg pairs (0,2),(1,3); w = e^{-2pi i t/256}, pair(1,3) gets w*(-i)
    __sincosf(-TWO_PI * (1.0f / 256.0f) * (float)t, &s, &c);
    {
        const float2 w0 = make_float2(c, s);
        const float2 w1 = make_float2(s, -c);          // w0 * (-i)
        float2 u0 = z[0], v0 = z[2], u1 = z[1], v1 = z[3];
        z[0] = make_float2(u0.x + v0.x, u0.y + v0.y);
        z[2] = cmul(make_float2(u0.x - v0.x, u0.y - v0.y), w0);
        z[1] = make_float2(u1.x + v1.x, u1.y + v1.y);
        z[3] = cmul(make_float2(u1.x - v1.x, u1.y - v1.y), w1);
    }
    // m=128: reg pairs (0,1),(2,3); w = e^{-2pi i t/128}
    __sincosf(-TWO_PI * (1.0f / 128.0f) * (float)t, &s, &c);
    {
        const float2 w = make_float2(c, s);
        float2 u0 = z[0], v0 = z[1], u1 = z[2], v1 = z[3];
        z[0] = make_float2(u0.x + v0.x, u0.y + v0.y);
        z[1] = cmul(make_float2(u0.x - v0.x, u0.y - v0.y), w);
        z[2] = make_float2(u1.x + v1.x, u1.y + v1.y);
        z[3] = cmul(make_float2(u1.x - v1.x, u1.y - v1.y), w);
    }
    // m=64..8: lane-xor m/2, w = e^{-2pi i (t&(m/2-1))/m}
    #pragma unroll
    for (int m = 64; m >= 8; m >>= 1) {
        const int hm = m >> 1;
        __sincosf((-TWO_PI / (float)m) * (float)(t & (hm - 1)), &s, &c);
        const float2 w = make_float2(c, s);
        const bool hi = (t & hm) != 0;
        #pragma unroll
        for (int r = 0; r < 4; ++r) {
            float2 o;
            o.x = __shfl_xor(z[r].x, hm, 64);
            o.y = __shfl_xor(z[r].y, hm, 64);
            if (hi) z[r] = cmul(make_float2(o.x - z[r].x, o.y - z[r].y), w);
            else    z[r] = make_float2(z[r].x + o.x, z[r].y + o.y);
        }
    }
    // m=4: lane-xor 2; w = 1 (t even) or -i (t odd)
    {
        const bool hi  = (t & 2) != 0;
        const bool odd = (t & 1) != 0;
        #pragma unroll
        for (int r = 0; r < 4; ++r) {
            float2 o;
            o.x = __shfl_xor(z[r].x, 2, 64);
            o.y = __shfl_xor(z[r].y, 2, 64);
            float2 d = hi ? make_float2(o.x - z[r].x, o.y - z[r].y)
                          : make_float2(z[r].x + o.x, z[r].y + o.y);
            if (hi && odd) d = make_float2(d.y, -d.x);   // * (-i)
            z[r] = d;
        }
    }
    // m=2: lane-xor 1
    {
        const bool hi = (t & 1) != 0;
        #pragma unroll
        for (int r = 0; r < 4; ++r) {
            float2 o;
            o.x = __shfl_xor(z[r].x, 1, 64);
            o.y = __shfl_xor(z[r].y, 1, 64);
            z[r] = hi ? make_float2(o.x - z[r].x, o.y - z[r].y)
                      : make_float2(z[r].x + o.x, z[r].y + o.y);
        }
    }
}

// 8 waves/block; each wave: coalesced nontemporal luma loads for a packed
// row-pair, wave FFT, per-wave LDS stash (padded stride); then block-
// cooperative unpack + coalesced transposed store: lanes e -> (k=e>>3,
// pair=e&7) give 64B-contiguous segments per k.
__global__ __launch_bounds__(512)
void rowfft_wave(const float* __restrict__ pred, const float* __restrict__ targ,
                 uint2* __restrict__ GT /* [NIMG][WH][128] uint2 = row-pair */,
                 float* __restrict__ gsum /* [NIMG][VLEN] */,
                 float* __restrict__ out) {
    __shared__ float zbuf[8][ZSTR];    // per wave: re[256] + im[256], swizzled
    const int tid  = threadIdx.x;
    const int t    = tid & 63;
    const int wid  = tid >> 6;         // 0..7
    const int b    = blockIdx.x;       // 0..1023
    const int img  = b >> 4;           // 16 blocks per image
    const int pair = ((b & 15) << 3) | wid;
    const int rowA = pair * 2;

    if ((b & 15) == 0) {
        if (tid < VLEN) gsum[img * VLEN + tid] = 0.0f;
    }
    if (b == 0 && tid == 0) out[0] = 0.0f;

    const float* src  = (img < 32) ? pred : targ;
    const float* base = src + (size_t)(img & 31) * (3 * H * W) + (size_t)rowA * W;

    float2 z[4];
    #pragma unroll
    for (int r = 0; r < 4; ++r) {
        const int n = t + (r << 6);
        const float aR = __builtin_nontemporal_load(base + n);
        const float aG = __builtin_nontemporal_load(base + H * W + n);
        const float aB = __builtin_nontemporal_load(base + 2 * H * W + n);
        const float bR = __builtin_nontemporal_load(base + W + n);
        const float bG = __builtin_nontemporal_load(base + H * W + W + n);
        const float bB = __builtin_nontemporal_load(base + 2 * H * W + W + n);
        z[r] = make_float2(0.299f * aR + 0.587f * aG + 0.114f * aB,
                           0.299f * bR + 0.587f * bG + 0.114f * bB);
    }

    wfft256(z, t);

    float* zr = zbuf[wid];
    float* zi = zr + 256;
    #pragma unroll
    for (int r = 0; r < 4; ++r) {
        const int x  = (int)(__brev((unsigned)(t + (r << 6))) >> 24);
        const int sx = x ^ (x >> 5);
        zr[sx] = z[r].x; zi[sx] = z[r].y;
    }
    __syncthreads();                   // all 8 waves' spectra visible

    // Block-cooperative unpack + store:
    // Ga[k] = (Z[k]+conj(Z[-k]))/2, Gb[k] = -i(Z[k]-conj(Z[-k]))/2
    uint2* dst = GT + (size_t)img * WH * 128;
    const int basePair = (b & 15) << 3;
    for (int e = tid; e < WH * 8; e += 512) {
        const int k  = e >> 3;
        const int lp = e & 7;
        const float* qr = zbuf[lp];
        const float* qi = qr + 256;
        const int kq = (256 - k) & 255;
        const int sk = k ^ (k >> 5), sq = kq ^ (kq >> 5);
        const float2 P = make_float2(qr[sk], qi[sk]);
        const float2 Q = make_float2(qr[sq], qi[sq]);
        const __half2 a  = __floats2half2_rn(0.5f * (P.x + Q.x), 0.5f * (P.y - Q.y));
        const __half2 bb = __floats2half2_rn(0.5f * (P.y + Q.y), 0.5f * (Q.x - P.x));
        uint2 pk;
        pk.x = __builtin_bit_cast(unsigned, a);
        pk.y = __builtin_bit_cast(unsigned, bb);
        dst[(size_t)k * 128 + basePair + lp] = pk;
    }
}

// 8 waves/block, one column-FFT per wave, coalesced loads from transposed GT.
// Fused log-power + radial binning into block-shared bins, one atomic flush.
__global__ __launch_bounds__(512)
void colfft_bin_t(const __half2* __restrict__ GT, float* __restrict__ gsum) {
    __shared__ float bins[VLEN];
    const int tid = threadIdx.x;
    const int t   = tid & 63;
    const int wid = tid >> 6;          // 0..7
    const int blk = blockIdx.x;        // 0..NIMG*17-1
    const int img = blk / 17;
    const int grp = blk - img * 17;
    const int j   = grp * 8 + wid;     // 0..135

    if (tid < VLEN) bins[tid] = 0.0f;
    __syncthreads();

    if (j < WH) {
        const __half2* col = GT + ((size_t)img * WH + j) * 256;
        float2 z[4];
        #pragma unroll
        for (int r = 0; r < 4; ++r)
            z[r] = __half22float2(col[t + (r << 6)]);

        wfft256(z, t);

        const int j2 = j * j;
        #pragma unroll
        for (int r = 0; r < 4; ++r) {
            const int n   = (int)(__brev((unsigned)(t + (r << 6))) >> 24);
            const int di  = (n < 128) ? n : n - 256;
            const int rad = isqrt_fast(di * di + j2);
            const float p = z[r].x * z[r].x + z[r].y * z[r].y + 1e-8f;
            atomicAdd(&bins[rad], 20.0f * __logf(p));
        }
    }
    __syncthreads();

    const int j0   = grp * 8;
    const int jmax = (j0 + 7 < WH) ? j0 + 7 : WH - 1;
    const int rmax = isqrt_fast(128 * 128 + jmax * jmax);
    float* gs = gsum + (size_t)img * VLEN;
    for (int v = j0 + tid; v <= rmax; v += 512)
        atomicAdd(&gs[v], bins[v]);
}

// 32 blocks, one per pred/target pair: per-block static bin counts, per-bin
// mean, min/max normalize both profiles, SSE partial -> atomicAdd into out.
__global__ __launch_bounds__(256)
void finish32(const float* __restrict__ gsum, float* __restrict__ out) {
    __shared__ int    scnt[VLEN];
    __shared__ float4 red4[256];
    __shared__ float  reds[256];
    const int tid = threadIdx.x;
    const int pr  = blockIdx.x;        // 0..31

    if (tid < VLEN) scnt[tid] = 0;
    __syncthreads();
    for (int e = tid; e < H * WH; e += 256) {
        const int k  = e / WH;
        const int j  = e - k * WH;
        const int di = (k < 128) ? k : k - 256;
        atomicAdd(&scnt[isqrt_fast(di * di + j * j)], 1);
    }
    __syncthreads();

    const bool val = tid < VLEN;
    float a = 0.0f, b = 0.0f;
    float4 mm = make_float4(1e30f, -1e30f, 1e30f, -1e30f);  // (min_a,max_a,min_b,max_b)
    if (val) {
        const float ic = 1.0f / (float)scnt[tid];
        a = gsum[(size_t)pr * VLEN + tid] * ic;
        b = gsum[(size_t)(pr + 32) * VLEN + tid] * ic;
        mm = make_float4(a, a, b, b);
    }
    red4[tid] = mm; __syncthreads();
    for (int off = 128; off > 0; off >>= 1) {
        if (tid < off) {
            const float4 o = red4[tid + off];
            red4[tid].x = fminf(red4[tid].x, o.x);
            red4[tid].y = fmaxf(red4[tid].y, o.y);
            red4[tid].z = fminf(red4[tid].z, o.z);
            red4[tid].w = fmaxf(red4[tid].w, o.w);
        }
        __syncthreads();
    }
    const float4 m = red4[0];
    const float inva = 1.0f / (m.y - m.x);
    const float invb = 1.0f / (m.w - m.z);
    const float d = val ? (a - m.x) * inva - (b - m.z) * invb : 0.0f;
    reds[tid] = d * d; __syncthreads();
    for (int off = 128; off > 0; off >>= 1) {
        if (tid < off) reds[tid] += reds[tid + off];
        __syncthreads();
    }
    if (tid == 0) atomicAdd(out, reds[0] * (1.0f / (float)(32 * VLEN)));
}

extern "C" void kernel_launch(void* const* d_in, const int* in_sizes, int n_in,
                              void* d_out, int out_size, void* d_ws, size_t ws_size,
                              hipStream_t stream) {
    const float* pred = (const float*)d_in[0];
    const float* targ = (const float*)d_in[1];
    float* out = (float*)d_out;

    char* ws = (char*)d_ws;
    uint2* GT = (uint2*)ws;                                      // NIMG*WH*128 uint2
    ws += (size_t)NIMG * WH * 128 * sizeof(uint2);
    float* gsum = (float*)ws;                                    // NIMG*VLEN floats

    rowfft_wave<<<NIMG * 16, 512, 0, stream>>>(pred, targ, GT, gsum, out);
    colfft_bin_t<<<NIMG * 17, 512, 0, stream>>>((const __half2*)GT, gsum);
    finish32<<<32, 256, 0, stream>>>(gsum, out);
}

// Round 14
// 50.698 us; speedup vs baseline: 1.0168x; 1.0168x over previous
//
#include <hip/hip_runtime.h>
#include <hip/hip_fp16.h>

#define H    256
#define W    256
#define WH   129            // W/2 + 1
#define VLEN 182            // max radial bin + 1
#define NIMG 64             // 32 pred + 32 target
#define TWO_PI 6.283185307179586f
#define ZSTR 516            // zbuf row stride in floats
#define NBLK_COL (NIMG * 17)

// Integer-exact floor(sqrt) for s2 <= 32768: v_sqrt_f32 trunc is off by at
// most 1; two branchless fixups.
__device__ __forceinline__ int isqrt_fast(int s2) {
    int r = (int)__builtin_amdgcn_sqrtf((float)s2);
    r -= (r * r > s2);
    r += ((r + 1) * (r + 1) <= s2);
    return r;
}

__device__ __forceinline__ float2 cmul(float2 a, float2 b) {
    return make_float2(a.x * b.x - a.y * b.y, a.x * b.y + a.y * b.x);
}

// 256-point DIF FFT held by one 64-lane wave; thread t owns positions
// i = t + 64r (r=0..3). On exit, position i holds X[bitrev8(i)].
__device__ __forceinline__ void wfft256(float2 z[4], int t) {
    float s, c;
    // m=256: reg pairs (0,2),(1,3); w = e^{-2pi i t/256}, pair(1,3) gets w*(-i)
    __sincosf(-TWO_PI * (1.0f / 256.0f) * (float)t, &s, &c);
    {
        const float2 w0 = make_float2(c, s);
        const float2 w1 = make_float2(s, -c);          // w0 * (-i)
        float2 u0 = z[0], v0 = z[2], u1 = z[1], v1 = z[3];
        z[0] = make_float2(u0.x + v0.x, u0.y + v0.y);
        z[2] = cmul(make_float2(u0.x - v0.x, u0.y - v0.y), w0);
        z[1] = make_float2(u1.x + v1.x, u1.y + v1.y);
        z[3] = cmul(make_float2(u1.x - v1.x, u1.y - v1.y), w1);
    }
    // m=128: reg pairs (0,1),(2,3); w = e^{-2pi i t/128}
    __sincosf(-TWO_PI * (1.0f / 128.0f) * (float)t, &s, &c);
    {
        const float2 w = make_float2(c, s);
        float2 u0 = z[0], v0 = z[1], u1 = z[2], v1 = z[3];
        z[0] = make_float2(u0.x + v0.x, u0.y + v0.y);
        z[1] = cmul(make_float2(u0.x - v0.x, u0.y - v0.y), w);
        z[2] = make_float2(u1.x + v1.x, u1.y + v1.y);
        z[3] = cmul(make_float2(u1.x - v1.x, u1.y - v1.y), w);
    }
    // m=64..8: lane-xor m/2, w = e^{-2pi i (t&(m/2-1))/m}
    #pragma unroll
    for (int m = 64; m >= 8; m >>= 1) {
        const int hm = m >> 1;
        __sincosf((-TWO_PI / (float)m) * (float)(t & (hm - 1)), &s, &c);
        const float2 w = make_float2(c, s);
        const bool hi = (t & hm) != 0;
        #pragma unroll
        for (int r = 0; r < 4; ++r) {
            float2 o;
            o.x = __shfl_xor(z[r].x, hm, 64);
            o.y = __shfl_xor(z[r].y, hm, 64);
            if (hi) z[r] = cmul(make_float2(o.x - z[r].x, o.y - z[r].y), w);
            else    z[r] = make_float2(z[r].x + o.x, z[r].y + o.y);
        }
    }
    // m=4: lane-xor 2; w = 1 (t even) or -i (t odd)
    {
        const bool hi  = (t & 2) != 0;
        const bool odd = (t & 1) != 0;
        #pragma unroll
        for (int r = 0; r < 4; ++r) {
            float2 o;
            o.x = __shfl_xor(z[r].x, 2, 64);
            o.y = __shfl_xor(z[r].y, 2, 64);
            float2 d = hi ? make_float2(o.x - z[r].x, o.y - z[r].y)
                          : make_float2(z[r].x + o.x, z[r].y + o.y);
            if (hi && odd) d = make_float2(d.y, -d.x);   // * (-i)
            z[r] = d;
        }
    }
    // m=2: lane-xor 1
    {
        const bool hi = (t & 1) != 0;
        #pragma unroll
        for (int r = 0; r < 4; ++r) {
            float2 o;
            o.x = __shfl_xor(z[r].x, 1, 64);
            o.y = __shfl_xor(z[r].y, 1, 64);
            z[r] = hi ? make_float2(o.x - z[r].x, o.y - z[r].y)
                      : make_float2(z[r].x + o.x, z[r].y + o.y);
        }
    }
}

// 8 waves/block; each wave: coalesced luma loads for a packed row-pair, wave
// FFT, per-wave LDS stash; block-cooperative unpack + coalesced transposed
// store. Blocks with (b&15)==0 zero gsum; block 0 resets the counter.
__global__ __launch_bounds__(512)
void rowfft_wave(const float* __restrict__ pred, const float* __restrict__ targ,
                 uint2* __restrict__ GT /* [NIMG][WH][128] uint2 = row-pair */,
                 float* __restrict__ gsum /* [NIMG][VLEN] */,
                 unsigned* __restrict__ counter) {
    __shared__ float zbuf[8][ZSTR];    // per wave: re[256] + im[256], swizzled
    const int tid  = threadIdx.x;
    const int t    = tid & 63;
    const int wid  = tid >> 6;         // 0..7
    const int b    = blockIdx.x;       // 0..1023
    const int img  = b >> 4;           // 16 blocks per image
    const int pair = ((b & 15) << 3) | wid;
    const int rowA = pair * 2;

    if ((b & 15) == 0) {
        if (tid < VLEN) gsum[img * VLEN + tid] = 0.0f;
    }
    if (b == 0 && tid == 0) *counter = 0u;

    const float* src  = (img < 32) ? pred : targ;
    const float* base = src + (size_t)(img & 31) * (3 * H * W) + (size_t)rowA * W;

    float2 z[4];
    #pragma unroll
    for (int r = 0; r < 4; ++r) {
        const int n = t + (r << 6);
        const float aR = __builtin_nontemporal_load(base + n);
        const float aG = __builtin_nontemporal_load(base + H * W + n);
        const float aB = __builtin_nontemporal_load(base + 2 * H * W + n);
        const float bR = __builtin_nontemporal_load(base + W + n);
        const float bG = __builtin_nontemporal_load(base + H * W + W + n);
        const float bB = __builtin_nontemporal_load(base + 2 * H * W + W + n);
        z[r] = make_float2(0.299f * aR + 0.587f * aG + 0.114f * aB,
                           0.299f * bR + 0.587f * bG + 0.114f * bB);
    }

    wfft256(z, t);

    float* zr = zbuf[wid];
    float* zi = zr + 256;
    #pragma unroll
    for (int r = 0; r < 4; ++r) {
        const int x  = (int)(__brev((unsigned)(t + (r << 6))) >> 24);
        const int sx = x ^ (x >> 5);
        zr[sx] = z[r].x; zi[sx] = z[r].y;
    }
    __syncthreads();                   // all 8 waves' spectra visible

    // Block-cooperative unpack + store:
    // Ga[k] = (Z[k]+conj(Z[-k]))/2, Gb[k] = -i(Z[k]-conj(Z[-k]))/2
    uint2* dst = GT + (size_t)img * WH * 128;
    const int basePair = (b & 15) << 3;
    for (int e = tid; e < WH * 8; e += 512) {
        const int k  = e >> 3;
        const int lp = e & 7;
        const float* qr = zbuf[lp];
        const float* qi = qr + 256;
        const int kq = (256 - k) & 255;
        const int sk = k ^ (k >> 5), sq = kq ^ (kq >> 5);
        const float2 P = make_float2(qr[sk], qi[sk]);
        const float2 Q = make_float2(qr[sq], qi[sq]);
        const __half2 a  = __floats2half2_rn(0.5f * (P.x + Q.x), 0.5f * (P.y - Q.y));
        const __half2 bb = __floats2half2_rn(0.5f * (P.y + Q.y), 0.5f * (Q.x - P.x));
        uint2 pk;
        pk.x = __builtin_bit_cast(unsigned, a);
        pk.y = __builtin_bit_cast(unsigned, bb);
        dst[(size_t)k * 128 + basePair + lp] = pk;
    }
}

// 8 waves/block, one column-FFT per wave, coalesced loads from transposed GT.
// Fused log-power + radial binning + atomic flush. Completion counter (NO
// device fence — flush atomics are drained with one vmcnt(0), counter atomic
// is then ordered after them); last block normalizes + writes MSE, reading
// gsum through coherent atomic loads.
__global__ __launch_bounds__(512)
void colfft_bin_finish(const __half2* __restrict__ GT,
                       float* __restrict__ gsum,
                       unsigned* __restrict__ counter,
                       float* __restrict__ out) {
    __shared__ float bins[VLEN];
    __shared__ int   scnt[VLEN];
    __shared__ float facc[8];
    __shared__ int   amLast;
    const int tid = threadIdx.x;
    const int t   = tid & 63;
    const int wid = tid >> 6;          // 0..7
    const int blk = blockIdx.x;        // 0..NBLK_COL-1
    const int img = blk / 17;
    const int grp = blk - img * 17;
    const int j   = grp * 8 + wid;     // 0..135

    if (tid < VLEN) bins[tid] = 0.0f;
    __syncthreads();

    if (j < WH) {
        const __half2* col = GT + ((size_t)img * WH + j) * 256;
        float2 z[4];
        #pragma unroll
        for (int r = 0; r < 4; ++r)
            z[r] = __half22float2(col[t + (r << 6)]);

        wfft256(z, t);

        const int j2 = j * j;
        #pragma unroll
        for (int r = 0; r < 4; ++r) {
            const int n   = (int)(__brev((unsigned)(t + (r << 6))) >> 24);
            const int di  = (n < 128) ? n : n - 256;
            const int rad = isqrt_fast(di * di + j2);
            const float p = z[r].x * z[r].x + z[r].y * z[r].y + 1e-8f;
            atomicAdd(&bins[rad], 20.0f * __logf(p));
        }
    }
    __syncthreads();

    const int j0   = grp * 8;
    const int jmax = (j0 + 7 < WH) ? j0 + 7 : WH - 1;
    const int rmax = isqrt_fast(128 * 128 + jmax * jmax);
    float* gs = gsum + (size_t)img * VLEN;
    for (int v = j0 + tid; v <= rmax; v += 512)
        atomicAdd(&gs[v], bins[v]);

    // ---- completion: drain own flush atomics, then count ----
    asm volatile("s_waitcnt vmcnt(0)" ::: "memory");
    __syncthreads();
    if (tid == 0) amLast = (atomicAdd(counter, 1u) == NBLK_COL - 1);
    __syncthreads();
    if (!amLast) return;

    // ---- last block: static bin counts, normalize, MSE ----
    if (tid < VLEN) scnt[tid] = 0;
    __syncthreads();
    for (int e = tid; e < H * WH; e += 512) {
        const int k  = e / WH;
        const int jj = e - k * WH;
        const int di = (k < 128) ? k : k - 256;
        atomicAdd(&scnt[isqrt_fast(di * di + jj * jj)], 1);
    }
    __syncthreads();

    float total = 0.0f;
    #pragma unroll
    for (int q = 0; q < 4; ++q) {
        const int pr = (wid << 2) + q;   // wave wid handles pairs 4*wid..4*wid+3
        float a[3], b[3];
        float mna = 1e30f, mnb = 1e30f, mxa = -1e30f, mxb = -1e30f;
        #pragma unroll
        for (int r = 0; r < 3; ++r) {
            const int v = t + (r << 6);
            if (v < VLEN) {
                const float ic = 1.0f / (float)scnt[v];
                a[r] = atomicAdd(&gsum[(size_t)pr * VLEN + v], 0.0f) * ic;
                b[r] = atomicAdd(&gsum[(size_t)(pr + 32) * VLEN + v], 0.0f) * ic;
                mna = fminf(mna, a[r]); mxa = fmaxf(mxa, a[r]);
                mnb = fminf(mnb, b[r]); mxb = fmaxf(mxb, b[r]);
            } else { a[r] = 0.0f; b[r] = 0.0f; }
        }
        #pragma unroll
        for (int m = 32; m >= 1; m >>= 1) {
            mna = fminf(mna, __shfl_xor(mna, m, 64));
            mxa = fmaxf(mxa, __shfl_xor(mxa, m, 64));
            mnb = fminf(mnb, __shfl_xor(mnb, m, 64));
            mxb = fmaxf(mxb, __shfl_xor(mxb, m, 64));
        }
        const float inva = 1.0f / (mxa - mna);
        const float invb = 1.0f / (mxb - mnb);
        float sacc = 0.0f;
        #pragma unroll
        for (int r = 0; r < 3; ++r) {
            const int v = t + (r << 6);
            if (v < VLEN) {
                const float d = (a[r] - mna) * inva - (b[r] - mnb) * invb;
                sacc += d * d;
            }
        }
        #pragma unroll
        for (int m = 32; m >= 1; m >>= 1) sacc += __shfl_xor(sacc, m, 64);
        total += sacc;
    }
    if (t == 0) facc[wid] = total;
    __syncthreads();
    if (tid == 0) {
        float r = 0.0f;
        for (int i = 0; i < 8; ++i) r += facc[i];
        out[0] = r / (float)(32 * VLEN);
    }
}

extern "C" void kernel_launch(void* const* d_in, const int* in_sizes, int n_in,
                              void* d_out, int out_size, void* d_ws, size_t ws_size,
                              hipStream_t stream) {
    const float* pred = (const float*)d_in[0];
    const float* targ = (const float*)d_in[1];
    float* out = (float*)d_out;

    char* ws = (char*)d_ws;
    uint2* GT = (uint2*)ws;                                      // NIMG*WH*128 uint2
    ws += (size_t)NIMG * WH * 128 * sizeof(uint2);
    float* gsum = (float*)ws;                                    // NIMG*VLEN floats
    ws += (size_t)NIMG * VLEN * sizeof(float);
    unsigned* counter = (unsigned*)ws;                           // 1 u32

    rowfft_wave<<<NIMG * 16, 512, 0, stream>>>(pred, targ, GT, gsum, counter);
    colfft_bin_finish<<<NBLK_COL, 512, 0, stream>>>((const __half2*)GT, gsum,
                                                    counter, out);
}